// Round 4
// baseline (178.817 us; speedup 1.0000x reference)
//
#include <hip/hip_runtime.h>

typedef __attribute__((ext_vector_type(8))) short bf16x8;
typedef __attribute__((ext_vector_type(4))) float f32x4;

#define SZQKV 12582912  // B*N*C = one (q|k|v) output block, elements

__device__ __forceinline__ unsigned short f2bf(float f) {
    unsigned int u = __float_as_uint(f);
    unsigned int r = (u + 0x7FFFu + ((u >> 16) & 1u)) >> 16;
    return (unsigned short)r;
}

#define GLDS16(g, l) __builtin_amdgcn_global_load_lds( \
    (const __attribute__((address_space(1))) unsigned int*)(g), \
    (__attribute__((address_space(3))) unsigned int*)(l), 16, 0, 0)

// ---------------- cast f32 -> bf16 into workspace ----------------
__global__ void cast_all(const float* __restrict__ x,
                         const float* __restrict__ wqkv,
                         const float* __restrict__ wproj,
                         unsigned short* __restrict__ dst) {
    const int T1 = 12582912;       // x
    const int T2 = T1 + 1769472;   // + w_qkv
    const int T3 = T2 + 589824;    // + w_proj
    int stride = gridDim.x * blockDim.x * 4;
    for (int base = (blockIdx.x * blockDim.x + threadIdx.x) * 4; base < T3; base += stride) {
        const float* src; int off;
        if (base < T1)      { src = x;     off = base; }
        else if (base < T2) { src = wqkv;  off = base - T1; }
        else                { src = wproj; off = base - T2; }
        float4 v = *(const float4*)(src + off);
        ushort4 o;
        o.x = f2bf(v.x); o.y = f2bf(v.y); o.z = f2bf(v.z); o.w = f2bf(v.w);
        *(ushort4*)(dst + base) = o;
    }
}

// ---------------- 256x256 GEMM, BK=64, 8 waves (2m x 4n), 128x64 per wave ----------------
// A: [M][768] bf16 row-major. Bw: [Nw][768] bf16 row-major (B^T input). K = 768 = 12 K-tiles.
// LDS: K-tile = A 256x64 (32KB) + B 256x64 (32KB) = 64KB; double-buffered = 128KB.
// Swizzle: 128B rows, 16B chunk j -> phys chunk j ^ (row&7); conflict-free wave64 b128 reads.
// Sync protocol (round-2-proven ordering; vmcnt is PER-WAVE so the own-tile wait must
// precede the barrier that publishes the buffer):
//   STAGE(kt+1) ; vmcnt(8)  [own tile-kt loads landed; tile kt+1 (8) stays in flight]
//   barrier                 [=> ALL waves' tile-kt loads landed]
//   4 compute phases (ds_read + 16 MFMA each, setprio)
//   lgkmcnt(0) ; barrier    [all waves done reading buf -> next STAGE may overwrite]
template <int MODE>
__global__ __launch_bounds__(512, 2) void gemm8(const unsigned short* __restrict__ A,
                                                const unsigned short* __restrict__ Bw,
                                                const float* __restrict__ bias,
                                                float* __restrict__ dout,
                                                int nby) {
    __shared__ unsigned char lds8[131072];
    const int t = threadIdx.x;
    const int lane = t & 63;
    const int w = t >> 6;
    const int wm = w >> 2;   // 0..1 -> 128 m-rows
    const int wn = w & 3;    // 0..3 -> 64 n-cols

    // bijective XCD chunk swizzle (grid % 8 == 0)
    const int cpx = gridDim.x >> 3;
    const int orig = blockIdx.x;
    const int wgid = (orig & 7) * cpx + (orig >> 3);
    const int bx = wgid / nby, by = wgid - bx * nby;
    const int m0 = bx * 256;
    const int n0 = by * 256;

    const unsigned char* Ab = (const unsigned char*)A;
    const unsigned char* Bb = (const unsigned char*)Bw;

    // staging: chunk c = l*512 + t (l=0..3 A, l=4..7 B); row = l*64 + (t>>3), j = t&7;
    // global src chunk = j ^ (row&7) (inverse swizzle), LDS dst linear c*16.
    const int trow = t >> 3;
    const int jx = ((t & 7) ^ (trow & 7)) << 4;
    const size_t aBase = (size_t)(m0 + trow) * 1536 + jx;
    const size_t bBase = (size_t)(n0 + trow) * 1536 + jx;
    const int ldst = t * 16;

    // fragment read geometry (phys chunk = logical ^ (row&7); row&7 == lane&7 here)
    const int rA = wm * 128 + (lane & 15);            // + mi*16 -> A row
    const int rB = wn * 64 + (lane & 15);             // + ni*16 -> B row
    const int xt0 = (((lane >> 4)) ^ (lane & 7)) << 4;      // ks=0 chunk
    const int xt1 = ((4 + (lane >> 4)) ^ (lane & 7)) << 4;  // ks=1 chunk

    f32x4 acc[8][4] = {};

#define STAGE(kt, bsel) do { \
    unsigned char* db_ = lds8 + (bsel) * 65536; \
    const size_t ko_ = (size_t)(kt) * 128; \
    GLDS16(Ab + aBase + ko_,          db_ + ldst); \
    GLDS16(Ab + aBase + ko_ + 98304,  db_ + ldst + 8192); \
    GLDS16(Ab + aBase + ko_ + 196608, db_ + ldst + 16384); \
    GLDS16(Ab + aBase + ko_ + 294912, db_ + ldst + 24576); \
    GLDS16(Bb + bBase + ko_,          db_ + 32768 + ldst); \
    GLDS16(Bb + bBase + ko_ + 98304,  db_ + 32768 + ldst + 8192); \
    GLDS16(Bb + bBase + ko_ + 196608, db_ + 32768 + ldst + 16384); \
    GLDS16(Bb + bBase + ko_ + 294912, db_ + 32768 + ldst + 24576); \
} while (0)

#define LDA4(base_, xt_) do { \
    _Pragma("unroll") \
    for (int mi = 0; mi < 4; ++mi) \
        av[mi] = *(const bf16x8*)(bufA + (rA + (base_) + mi * 16) * 128 + (xt_)); \
} while (0)

#define LDB4(xt_) do { \
    _Pragma("unroll") \
    for (int ni = 0; ni < 4; ++ni) \
        bv[ni] = *(const bf16x8*)(bufB + (rB + ni * 16) * 128 + (xt_)); \
} while (0)

#define MM(rbase_) do { \
    __builtin_amdgcn_s_setprio(1); \
    _Pragma("unroll") \
    for (int mi = 0; mi < 4; ++mi) \
    _Pragma("unroll") \
    for (int ni = 0; ni < 4; ++ni) \
        acc[(rbase_) + mi][ni] = __builtin_amdgcn_mfma_f32_16x16x32_bf16(av[mi], bv[ni], acc[(rbase_) + mi][ni], 0, 0, 0); \
    __builtin_amdgcn_s_setprio(0); \
} while (0)

    STAGE(0, 0);
    for (int kt = 0; kt < 12; ++kt) {
        if (kt < 11) {
            STAGE(kt + 1, (kt + 1) & 1);
            asm volatile("s_waitcnt vmcnt(8)" ::: "memory");  // own tile-kt landed
        } else {
            asm volatile("s_waitcnt vmcnt(0)" ::: "memory");
        }
        __builtin_amdgcn_s_barrier();   // publish tile kt to all waves
        asm volatile("" ::: "memory");
        const unsigned char* bufA = lds8 + (kt & 1) * 65536;
        const unsigned char* bufB = bufA + 32768;
        bf16x8 av[4], bv[4];
        // phase 0: ks=0, mi 0..3
        LDA4(0, xt0); LDB4(xt0); MM(0);
        // phase 1: ks=0, mi 4..7 (reuse bv)
        LDA4(64, xt0); MM(4);
        // phase 2: ks=1, mi 0..3
        LDA4(0, xt1); LDB4(xt1); MM(0);
        // phase 3: ks=1, mi 4..7
        LDA4(64, xt1); MM(4);
        // all our ds_reads done before allowing buffer overwrite next iter
        asm volatile("s_waitcnt lgkmcnt(0)" ::: "memory");
        __builtin_amdgcn_s_barrier();
        asm volatile("" ::: "memory");
    }
#undef STAGE
#undef LDA4
#undef LDB4
#undef MM

    const int crow = (lane >> 4) * 4;  // C row (+reg r)
    const int ccol = lane & 15;        // C col
    if (MODE == 0) {
        const int b = m0 >> 12;        // batch (256 | 4096)
        const int n_base = m0 & 4095;
#pragma unroll
        for (int mi = 0; mi < 8; ++mi) {
            int n = n_base + wm * 128 + mi * 16 + crow;  // 4 consecutive n (regs)
#pragma unroll
            for (int ni = 0; ni < 4; ++ni) {
                int o = n0 + wn * 64 + ni * 16 + ccol;   // column in [0,2304)
                int sel = o / 768;                       // 0=q 1=k 2=v
                int rem = o - sel * 768;                 // dil*256 + c'
                float* dst = dout + (size_t)(3 - sel) * SZQKV
                           + ((size_t)((rem >> 8) * 4 + b) * 256 + (rem & 255)) * 4096 + n;
                *(f32x4*)dst = acc[mi][ni];
            }
        }
    } else {
#pragma unroll
        for (int mi = 0; mi < 8; ++mi) {
            int m = m0 + wm * 128 + mi * 16 + crow;
#pragma unroll
            for (int ni = 0; ni < 4; ++ni) {
                int o = n0 + wn * 64 + ni * 16 + ccol;
                float bb = bias[o];
#pragma unroll
                for (int r = 0; r < 4; ++r)
                    dout[(size_t)(m + r) * 768 + o] = acc[mi][ni][r] + bb;
            }
        }
    }
}

// ---------------- attention: read q/k/v f32 from d_out, write bf16 [b][n][c] ----------------
__global__ __launch_bounds__(256) void attn_kernel(const float* __restrict__ qkv,
                                                   unsigned short* __restrict__ attnbf) {
    const int chunk = blockIdx.x;  // 64 chunks of 64 n
    const int dil_i = blockIdx.y;  // 0..2
    const int b     = blockIdx.z;  // 0..3
    const int dil   = dil_i + 1;
    const int t  = threadIdx.x;
    const int h  = t >> 6;         // wave = head
    const int nl = t & 63;
    const int n  = chunk * 64 + nl;

    const size_t gb = (size_t)(dil_i * 4 + b) * 256 * 4096;
    const float* Q = qkv + (size_t)3 * SZQKV + gb;
    const float* K = qkv + (size_t)2 * SZQKV + gb;
    const float* V = qkv + (size_t)1 * SZQKV + gb;

    const int nm = n - dil, np = n + dil;
    const bool vm = (nm >= 0), vp = (np < 4096);
    const int nmc = vm ? nm : 0, npc = vp ? np : 4095;

    float s0 = 0.f, s1 = 0.f, s2 = 0.f;
    {
        const float* qrow = Q + (size_t)h * 64 * 4096;
        const float* krow = K + (size_t)h * 64 * 4096;
        for (int d = 0; d < 64; ++d) {
            float q = qrow[n];
            s0 += q * krow[nmc];
            s1 += q * krow[n];
            s2 += q * krow[npc];
            qrow += 4096; krow += 4096;
        }
    }
    s0 = vm ? s0 * 0.125f : 0.f;   // padded K-column -> exact 0 score (matches ref)
    s1 *= 0.125f;
    s2 = vp ? s2 * 0.125f : 0.f;
    float mx = fmaxf(0.f, fmaxf(s0, fmaxf(s1, s2)));
    float e0 = __expf(s0 - mx), e1 = __expf(s1 - mx), e2 = __expf(s2 - mx);
    // softmax over 9 slots: 6 structural zeros contribute 6*exp(-mx)
    float den = e0 + e1 + e2 + 6.f * __expf(-mx);
    float inv = 1.f / den;
    float p0 = vm ? e0 * inv : 0.f;
    float p1 = e1 * inv;
    float p2 = vp ? e2 * inv : 0.f;

    __shared__ unsigned short lout[256][65];  // [c'][n] bf16, padded row
    {
        const float* vrow = V + (size_t)h * 64 * 4096;
        for (int d = 0; d < 64; ++d) {
            float o = p0 * vrow[nmc] + p1 * vrow[n] + p2 * vrow[npc];
            lout[h * 64 + d][nl] = f2bf(o);
            vrow += 4096;
        }
    }
    __syncthreads();

    // write tile transposed: attnbf[(b*4096+n)*768 + dil_i*256 + c], c fastest
#pragma unroll
    for (int i = 0; i < 8; ++i) {
        int linear = i * 256 + t;   // 0..2047
        int nn   = linear >> 5;     // 0..63
        int cblk = linear & 31;     // 0..31 (8 channels each)
        union { unsigned short u[8]; f32x4 v; } tt;
#pragma unroll
        for (int j = 0; j < 8; ++j) tt.u[j] = lout[cblk * 8 + j][nn];
        unsigned short* dst = attnbf + (size_t)(b * 4096 + chunk * 64 + nn) * 768
                            + dil_i * 256 + cblk * 8;
        *(f32x4*)dst = tt.v;
    }
}

extern "C" void kernel_launch(void* const* d_in, const int* in_sizes, int n_in,
                              void* d_out, int out_size, void* d_ws, size_t ws_size,
                              hipStream_t stream) {
    const float* x     = (const float*)d_in[0];
    const float* wqkv  = (const float*)d_in[1];
    const float* wproj = (const float*)d_in[2];
    const float* bproj = (const float*)d_in[3];
    float* out = (float*)d_out;

    unsigned short* xbf     = (unsigned short*)d_ws;          // 12582912
    unsigned short* wqkvbf  = xbf + 12582912;                 // 1769472
    unsigned short* wprojbf = wqkvbf + 1769472;               // 589824
    unsigned short* attnbf  = wprojbf + 589824;               // 12582912

    cast_all<<<2048, 256, 0, stream>>>(x, wqkv, wproj, xbf);

    // qkv: M=16384 (64 m-tiles), Nw=2304 (9 n-tiles) -> 576 blocks (%8==0)
    gemm8<0><<<dim3(576), 512, 0, stream>>>(xbf, wqkvbf, nullptr, out, 9);

    attn_kernel<<<dim3(64, 3, 4), 256, 0, stream>>>(out, attnbf);

    // proj: M=16384, Nw=768 (3 n-tiles) -> 192 blocks (%8==0)
    gemm8<1><<<dim3(192), 512, 0, stream>>>(attnbf, wprojbf, bproj, out, 3);
}